// Round 6
// baseline (152.337 us; speedup 1.0000x reference)
//
#include <hip/hip_runtime.h>
#include <hip/hip_bf16.h>
#include <math.h>

// Problem constants
#define Bb   32
#define Ss   512
#define Hh   768
#define Dd   64
#define ND   128          // 2*D
#define Mrows (Bb*Ss)     // 16384
#define BIGF 1.0e12f

typedef __attribute__((ext_vector_type(8))) short short8;   // 8 bf16
typedef __attribute__((ext_vector_type(4))) float floatx4;  // 4 f32 acc

__device__ __forceinline__ short f2bf(float x) {
    unsigned u = __builtin_bit_cast(unsigned, x);
    u = (u + 0x7FFF + ((u >> 16) & 1)) >> 16;   // RNE
    return (short)u;
}

// ---------------------------------------------------------------------------
// Kernel 0: w (768,128) f32 -> wfrag in MFMA-fragment-major bf16 layout:
//   wfrag[((tt*24 + c)*64 + lane)*8 + j]  (tt = h*4+t)
//   maps to  n = tt*16 + (lane&15),  k = c*32 + (lane>>4)*8 + j
// Also builds the RoPE sin/cos table.
// ---------------------------------------------------------------------------
__global__ __launch_bounds__(256) void prep_kernel(
    const float* __restrict__ w, short* __restrict__ wfrag,
    float2* __restrict__ rt)                   // rt[spos*32 + i] = (sin, cos)
{
    int idx = blockIdx.x * 256 + threadIdx.x;  // 98304 total
    int j    = idx & 7;
    int lane = (idx >> 3) & 63;
    int rest = idx >> 9;                       // tt*24 + c
    int c    = rest % 24;
    int tt   = rest / 24;
    int n    = tt * 16 + (lane & 15);
    int k    = c * 32 + (lane >> 4) * 8 + j;
    wfrag[idx] = f2bf(w[k * ND + n]);
    if (idx < Ss * 32) {
        int spos = idx >> 5;
        int i    = idx & 31;
        float ln_base = -logf(10000.0f) / 32.0f;
        float invf = expf(ln_base * (float)i);
        float sn, cs;
        sincosf((float)spos * invf, &sn, &cs);
        rt[idx] = make_float2(sn, cs);
    }
}

// ---------------------------------------------------------------------------
// Kernel 0b: pack span bits. Thread reads one int (coalesced); __ballot
// packs 64 preds; lanes 0/32 store the two uint32 words. Bit n&31 order.
// ---------------------------------------------------------------------------
__global__ __launch_bounds__(256) void pack_kernel(
    const int* __restrict__ span, unsigned* __restrict__ spack)
{
    int gid = blockIdx.x * 256 + threadIdx.x;
    int lane = threadIdx.x & 63;
    unsigned long long m = __ballot(span[gid] != 0);
    if ((gid & 31) == 0)
        spack[gid >> 5] = (unsigned)(m >> (lane & 32));
}

// ---------------------------------------------------------------------------
// Kernel 1: MFMA bf16 projection + bias + RoPE -> q/k (bf16).
// Grid 512 x 512thr (8 waves): wave = (rowgrp, h, khalf). K split in two ->
// 12-chunk chains per wave, 4 waves/SIMD for latency hiding; kh=1 partials
// combined via LDS ([idx][lane] layout: conflict-free, 2 lanes/bank).
// __launch_bounds__(512,4): R4 post-mortem — default heuristic capped VGPRs
// and destroyed the register double-buffer (scratch/serialization).
// ---------------------------------------------------------------------------
__global__ __launch_bounds__(512, 4) void proj_rope_kernel(
    const float*  __restrict__ hidden,   // (M, H) f32
    const short*  __restrict__ wfrag,    // fragment-major bf16 (see prep)
    const float*  __restrict__ bias,     // (128,) f32
    const float2* __restrict__ rt,       // (512, 32) sin/cos
    short* __restrict__ qbf,             // (M, 64) bf16
    short* __restrict__ kbf)             // (M, 64) bf16
{
    const int tid   = threadIdx.x;
    const int w     = tid >> 6;          // wave 0..7
    const int lane  = tid & 63;
    const int quad  = lane >> 4;
    const int l15   = lane & 15;
    const int rg    = w & 1;             // row group (16 rows)
    const int h     = (w >> 1) & 1;      // 0 = q cols, 1 = k cols
    const int kh    = w >> 2;            // K half (chunks kh*12 .. +11)
    const int mrow0 = blockIdx.x * 32 + rg * 16;

    const float* ap  = hidden + (size_t)(mrow0 + l15) * Hh + quad * 8
                              + kh * 12 * 32;
    const short* bp0 = wfrag + (size_t)(h * 4) * 24 * 512 + lane * 8
                             + kh * 12 * 512;

    floatx4 acc[4] = {{0.f,0.f,0.f,0.f},{0.f,0.f,0.f,0.f},
                      {0.f,0.f,0.f,0.f},{0.f,0.f,0.f,0.f}};

    float4 A0[2], A1[2];
    short8 Bf[2][4];

#define PLOAD(buf, c) do {                                        \
    A0[buf] = *(const float4*)(ap + (c) * 32);                    \
    A1[buf] = *(const float4*)(ap + (c) * 32 + 4);                \
    Bf[buf][0] = *(const short8*)(bp0 + 0 * 24 * 512 + (c) * 512);\
    Bf[buf][1] = *(const short8*)(bp0 + 1 * 24 * 512 + (c) * 512);\
    Bf[buf][2] = *(const short8*)(bp0 + 2 * 24 * 512 + (c) * 512);\
    Bf[buf][3] = *(const short8*)(bp0 + 3 * 24 * 512 + (c) * 512);\
} while (0)

#define PCOMP(buf) do {                                         \
    short8 av;                                                  \
    av[0] = f2bf(A0[buf].x); av[1] = f2bf(A0[buf].y);           \
    av[2] = f2bf(A0[buf].z); av[3] = f2bf(A0[buf].w);           \
    av[4] = f2bf(A1[buf].x); av[5] = f2bf(A1[buf].y);           \
    av[6] = f2bf(A1[buf].z); av[7] = f2bf(A1[buf].w);           \
    acc[0] = __builtin_amdgcn_mfma_f32_16x16x32_bf16(av, Bf[buf][0], acc[0], 0, 0, 0); \
    acc[1] = __builtin_amdgcn_mfma_f32_16x16x32_bf16(av, Bf[buf][1], acc[1], 0, 0, 0); \
    acc[2] = __builtin_amdgcn_mfma_f32_16x16x32_bf16(av, Bf[buf][2], acc[2], 0, 0, 0); \
    acc[3] = __builtin_amdgcn_mfma_f32_16x16x32_bf16(av, Bf[buf][3], acc[3], 0, 0, 0); \
} while (0)

    PLOAD(0, 0);
    #pragma unroll
    for (int cc = 0; cc < 6; ++cc) {
        if (2 * cc + 1 < 12) PLOAD(1, 2 * cc + 1);
        PCOMP(0);
        if (2 * cc + 2 < 12) PLOAD(0, 2 * cc + 2);
        PCOMP(1);
    }
#undef PLOAD
#undef PCOMP

    // ---- combine K halves through LDS (slot = rg*2+h = w&3)
    __shared__ float lacc[4][16][64];    // [slot][t*4+reg][lane] 16 KB
    const int slot = w & 3;
    if (kh == 1) {
        #pragma unroll
        for (int t = 0; t < 4; ++t)
            #pragma unroll
            for (int reg = 0; reg < 4; ++reg)
                lacc[slot][t * 4 + reg][lane] = acc[t][reg];
    }
    __syncthreads();
    if (kh == 1) return;

    #pragma unroll
    for (int t = 0; t < 4; ++t)
        #pragma unroll
        for (int reg = 0; reg < 4; ++reg)
            acc[t][reg] += lacc[slot][t * 4 + reg][lane];

    // ---- Epilogue: bias + RoPE (table) -> bf16 store.
    short* dst = h ? kbf : qbf;
    const float* bptr = bias + h * 64;

    #pragma unroll
    for (int t = 0; t < 4; ++t) {
        const int d  = t * 16 + l15;               // 0..63 within q/k half
        const float bz = bptr[d];
        const float2* rtp = rt + (d >> 1);
        #pragma unroll
        for (int reg = 0; reg < 4; ++reg) {
            const int grow = mrow0 + quad * 4 + reg;
            const int spos = grow & (Ss - 1);
            float2 sc = rtp[spos * 32];
            float x  = acc[t][reg] + bz;
            float xo = __shfl_xor(x, 1);
            float o  = (d & 1) ? (x * sc.y + xo * sc.x)
                               : (x * sc.y - xo * sc.x);
            dst[(size_t)grow * Dd + d] = f2bf(o);
        }
    }
}

// ---------------------------------------------------------------------------
// Kernel 2: MFMA QK^T + masks + dual logsumexp.
// Grid: 32 batches x 16 slices of 32 rows; 512 threads (8 waves).
// span bits come from spack: 16 broadcast word loads per thread (words are
// quad-uniform) instead of 32 gathered ints (R5) — less latency + pressure.
// ---------------------------------------------------------------------------
__global__ __launch_bounds__(512, 4) void span_loss_kernel(
    const short* __restrict__ qbf,      // (M, 64) bf16
    const short* __restrict__ kbf,      // (M, 64) bf16
    const float* __restrict__ mask,     // (B, S)
    const unsigned* __restrict__ spack, // (M, 16) packed span bits
    double* __restrict__ rowsum)        // (M,)
{
    const int b    = blockIdx.x >> 4;
    const int m0   = (blockIdx.x & 15) * 32;
    const int tid  = threadIdx.x;
    const int w    = tid >> 6;
    const int lane = tid & 63;
    const int quad = lane >> 4;
    const int l15  = lane & 15;
    const int rh   = w & 1;              // row half (16 rows)
    const int cg   = w >> 1;             // col group (128 cols)
    const int rbase = m0 + rh * 16;      // + quad*4 + reg   (within batch)
    const int cbase = cg * 128;          // + t*16 + l15

    __shared__ float part[2][4][32];     // [neg/pos][colgroup][row]
    __shared__ float bred[2][32];

    // ---- A frags (Q): rows rbase + l15
    const short* qp = qbf + (size_t)(b * Ss + rbase + l15) * Dd + quad * 8;
    short8 a0 = *(const short8*)(qp);
    short8 a1 = *(const short8*)(qp + 32);

    // ---- packed span words (quad-uniform broadcast) + mask
    unsigned spw[4][4];
    float pdv[8];
    {
        const unsigned* spp = spack
            + (size_t)(b * Ss + rbase + quad * 4) * 16 + cg * 4;
        #pragma unroll
        for (int reg = 0; reg < 4; ++reg)
            #pragma unroll
            for (int g = 0; g < 4; ++g)
                spw[reg][g] = spp[reg * 16 + g];
        #pragma unroll
        for (int t = 0; t < 8; ++t)
            pdv[t] = mask[b * Ss + cbase + t * 16 + l15];
    }

    floatx4 acc[8];
    #pragma unroll
    for (int t = 0; t < 8; ++t) acc[t] = (floatx4){0.f, 0.f, 0.f, 0.f};

    // ---- B frags (K): cols cbase + t*16 + l15; two K-chunks.
    const short* kp = kbf + (size_t)(b * Ss + cbase + l15) * Dd + quad * 8;
    #pragma unroll
    for (int t = 0; t < 8; ++t) {
        short8 bv = *(const short8*)(kp + (size_t)t * 16 * Dd);
        acc[t] = __builtin_amdgcn_mfma_f32_16x16x32_bf16(a0, bv, acc[t], 0, 0, 0);
    }
    #pragma unroll
    for (int t = 0; t < 8; ++t) {
        short8 bv = *(const short8*)(kp + (size_t)t * 16 * Dd + 32);
        acc[t] = __builtin_amdgcn_mfma_f32_16x16x32_bf16(a1, bv, acc[t], 0, 0, 0);
    }

    // ---- Epilogue: dots -> yp in place; gather span bits into spb.
    unsigned spb = 0;
    #pragma unroll
    for (int t = 0; t < 8; ++t) {
        const int n = cbase + t * 16 + l15;
        const float pd = pdv[t];
        const int sh = (t & 1) * 16 + l15;
        #pragma unroll
        for (int reg = 0; reg < 4; ++reg) {
            const int m = rbase + quad * 4 + reg;
            unsigned bit = (spw[reg][t >> 1] >> sh) & 1u;
            float logit = acc[t][reg] * pd - (1.0f - pd) * BIGF;
            if (n < m) logit -= BIGF;
            logit *= 0.125f;
            float ft = (float)bit;
            acc[t][reg] = (1.0f - 2.0f * ft) * logit;   // yp
            spb |= bit << (t * 4 + reg);
        }
    }

    // ---- Pass 1: max (zero entry folded via init 0).
    float mxn[4] = {0.f, 0.f, 0.f, 0.f};
    float mxp[4] = {0.f, 0.f, 0.f, 0.f};
    #pragma unroll
    for (int t = 0; t < 8; ++t) {
        #pragma unroll
        for (int reg = 0; reg < 4; ++reg) {
            float ft = (float)((spb >> (t * 4 + reg)) & 1u);
            float yp = acc[t][reg];
            mxn[reg] = fmaxf(mxn[reg], yp - ft * BIGF);
            mxp[reg] = fmaxf(mxp[reg], yp - (1.0f - ft) * BIGF);
        }
    }
    #pragma unroll
    for (int off = 1; off < 16; off <<= 1) {
        #pragma unroll
        for (int reg = 0; reg < 4; ++reg) {
            mxn[reg] = fmaxf(mxn[reg], __shfl_xor(mxn[reg], off));
            mxp[reg] = fmaxf(mxp[reg], __shfl_xor(mxp[reg], off));
        }
    }
    if (l15 == 0) {
        #pragma unroll
        for (int reg = 0; reg < 4; ++reg) {
            part[0][cg][rh * 16 + quad * 4 + reg] = mxn[reg];
            part[1][cg][rh * 16 + quad * 4 + reg] = mxp[reg];
        }
    }
    __syncthreads();
    if (tid < 64) {
        int np = tid >> 5, r = tid & 31;
        float mv = fmaxf(fmaxf(part[np][0][r], part[np][1][r]),
                         fmaxf(part[np][2][r], part[np][3][r]));
        bred[np][r] = mv;
    }
    __syncthreads();

    // ---- Pass 2: sum of exp(v - max).
    float bmn[4], bmp[4];
    #pragma unroll
    for (int reg = 0; reg < 4; ++reg) {
        bmn[reg] = bred[0][rh * 16 + quad * 4 + reg];
        bmp[reg] = bred[1][rh * 16 + quad * 4 + reg];
    }
    float smn[4] = {0.f, 0.f, 0.f, 0.f};
    float smp[4] = {0.f, 0.f, 0.f, 0.f};
    #pragma unroll
    for (int t = 0; t < 8; ++t) {
        #pragma unroll
        for (int reg = 0; reg < 4; ++reg) {
            float ft = (float)((spb >> (t * 4 + reg)) & 1u);
            float yp = acc[t][reg];
            smn[reg] += __expf(yp - ft * BIGF - bmn[reg]);
            smp[reg] += __expf(yp - (1.0f - ft) * BIGF - bmp[reg]);
        }
    }
    #pragma unroll
    for (int off = 1; off < 16; off <<= 1) {
        #pragma unroll
        for (int reg = 0; reg < 4; ++reg) {
            smn[reg] += __shfl_xor(smn[reg], off);
            smp[reg] += __shfl_xor(smp[reg], off);
        }
    }
    if (l15 == 0) {
        #pragma unroll
        for (int reg = 0; reg < 4; ++reg) {
            part[0][cg][rh * 16 + quad * 4 + reg] = smn[reg];
            part[1][cg][rh * 16 + quad * 4 + reg] = smp[reg];
        }
    }
    __syncthreads();

    if (tid < 32) {
        int r = tid;
        float SN = __expf(-bred[0][r])
                 + part[0][0][r] + part[0][1][r] + part[0][2][r] + part[0][3][r];
        float SP = __expf(-bred[1][r])
                 + part[1][0][r] + part[1][1][r] + part[1][2][r] + part[1][3][r];
        float lse = (bred[0][r] + logf(SN)) + (bred[1][r] + logf(SP));
        rowsum[(size_t)(b * Ss + m0 + r)] = (double)lse;
    }
}

// ---------------------------------------------------------------------------
// Kernel 3: fp64 mean over 16384 row sums -> fp32 scalar.
// ---------------------------------------------------------------------------
__global__ __launch_bounds__(1024) void final_reduce_kernel(
    const double* __restrict__ rowsum, float* __restrict__ out)
{
    __shared__ double sh[1024];
    const int tid = threadIdx.x;
    double s = 0.0;
    #pragma unroll
    for (int i = 0; i < 16; ++i) s += rowsum[tid + i * 1024];
    sh[tid] = s;
    __syncthreads();
    for (int off = 512; off > 0; off >>= 1) {
        if (tid < off) sh[tid] += sh[tid + off];
        __syncthreads();
    }
    if (tid == 0) out[0] = (float)(sh[0] / (double)Mrows);
}

// ---------------------------------------------------------------------------
extern "C" void kernel_launch(void* const* d_in, const int* in_sizes, int n_in,
                              void* d_out, int out_size, void* d_ws, size_t ws_size,
                              hipStream_t stream)
{
    const float* hidden = (const float*)d_in[0];   // (B,S,H)
    const float* mask   = (const float*)d_in[1];   // (B,S)
    const int*   span   = (const int*)  d_in[2];   // (B,S,S)
    const float* w      = (const float*)d_in[3];   // (H, 2D)
    const float* bias   = (const float*)d_in[4];   // (2D,)
    float* out = (float*)d_out;

    // ws layout:
    //  [rowsum: 16384 f64           = 131072 B]
    //  [wfrag:  98304 bf16          = 196608 B]
    //  [rt:     16384 float2        = 131072 B]
    //  [spack:  16384*16 u32        = 1 MB]
    //  [qbf:    16384*64 bf16       = 2 MB]
    //  [kbf:    16384*64 bf16       = 2 MB]
    char* p = (char*)d_ws;
    double*   rowsum = (double*)p;          p += 131072;
    short*    wfrag  = (short*)p;           p += 196608;
    float2*   rt     = (float2*)p;          p += 131072;
    unsigned* spack  = (unsigned*)p;        p += (size_t)Mrows * 16 * 4;
    short*    qbf    = (short*)p;           p += (size_t)Mrows * Dd * 2;
    short*    kbf    = (short*)p;

    prep_kernel<<<Hh * ND / 256, 256, 0, stream>>>(w, wfrag, rt);
    pack_kernel<<<Mrows * Ss / 256, 256, 0, stream>>>(span, spack);
    proj_rope_kernel<<<Mrows / 32, 512, 0, stream>>>(hidden, wfrag, bias, rt, qbf, kbf);
    span_loss_kernel<<<Bb * 16, 512, 0, stream>>>(qbf, kbf, mask, spack, rowsum);
    final_reduce_kernel<<<1, 1024, 0, stream>>>(rowsum, out);
}